// Round 9
// baseline (199.694 us; speedup 1.0000x reference)
//
#include <hip/hip_runtime.h>

#define SEQ 2048
#define DMODEL 2048
#define NHEAD 16
#define EHEAD 128
#define NE3 384   // 3*EHEAD

using short8 = __attribute__((ext_vector_type(8))) short;
using f32x4  = __attribute__((ext_vector_type(4))) float;
using f32x16 = __attribute__((ext_vector_type(16))) float;
using uint4v = __attribute__((ext_vector_type(4))) unsigned int;
using uint2v = __attribute__((ext_vector_type(2))) unsigned int;

__device__ __forceinline__ unsigned short f32_to_bf16(float f) {
    unsigned int u = __float_as_uint(f);
    unsigned int rounding = 0x7fffu + ((u >> 16) & 1u);
    u += rounding;
    return (unsigned short)(u >> 16);
}

// async global->LDS, 16B/lane; LDS dest = wave-uniform base + lane*16B.
__device__ __forceinline__ void async_load16(const void* g, void* l) {
    __builtin_amdgcn_global_load_lds(
        (const __attribute__((address_space(1))) unsigned int*)g,
        (__attribute__((address_space(3))) unsigned int*)l, 16, 0, 0);
}

// ---------------- fused prep: cast x (blocks 0..4095) + transpose w (4096..7167) ----------------
__global__ void prep_kernel(const float* __restrict__ x, unsigned short* __restrict__ xb,
                            const float* __restrict__ w, unsigned short* __restrict__ wT) {
    __shared__ float tile[64][65];
    const int bid = blockIdx.x;
    if (bid < 4096) {
        int i = (bid * blockDim.x + threadIdx.x) * 4;
        float4 v = *(const float4*)(x + i);
        ushort4 o = make_ushort4(f32_to_bf16(v.x), f32_to_bf16(v.y), f32_to_bf16(v.z), f32_to_bf16(v.w));
        *(ushort4*)(xb + i) = o;
        return;
    }
    const int b = bid - 4096;          // 3072 transpose blocks: h 16 x n0 6 x d0 32
    const int h  = b / 192;
    const int r6 = b % 192;
    const int n0 = (r6 / 32) * 64;
    const int d0 = (r6 % 32) * 64;
    int t = threadIdx.x;
    int rr = t >> 4;           // 0..15
    int cc = (t & 15) * 4;     // 0..60
#pragma unroll
    for (int i = 0; i < 4; i++) {
        float4 v = *(const float4*)&w[(size_t)(h * DMODEL + d0 + rr + i * 16) * NE3 + n0 + cc];
        tile[rr + i * 16][cc + 0] = v.x;
        tile[rr + i * 16][cc + 1] = v.y;
        tile[rr + i * 16][cc + 2] = v.z;
        tile[rr + i * 16][cc + 3] = v.w;
    }
    __syncthreads();
#pragma unroll
    for (int i = 0; i < 4; i++) {
        int n = rr + i * 16;
        ushort4 o;
        o.x = f32_to_bf16(tile[cc + 0][n]);
        o.y = f32_to_bf16(tile[cc + 1][n]);
        o.z = f32_to_bf16(tile[cc + 2][n]);
        o.w = f32_to_bf16(tile[cc + 3][n]);
        *(ushort4*)&wT[(size_t)(h * NE3 + n0 + n) * DMODEL + d0 + cc] = o;
    }
}

// ---------------- QKV projection: 128x192 tile, 4 waves, ring-3, 2 blocks/CU ----------------
// r9: same merged single-phase K-step as r8 (1 barrier / 24 MFMA, verified) but the
// tile is halved in N so TWO independent blocks share a CU (ring-3 x 20 KB = 60 KB;
// 2 x 60 <= 160 KB). 512 blocks = exactly 2/CU -> two independent barrier domains
// interleave at stalls (m97-structure evidence: ~+10-15%). Per-wave output still
// 64x96 (wm=wave>>1, wn=wave&1) — fragment code/swizzle byte-identical to r8.
// Ring-3: at tile t (buf t%3) stage tile t+2 into buf (t+2)%3 = (t-1)%3 (that
// buf's last reads drained by t-1's lgkmcnt(0)+barrier). Gates: vmcnt(5) steady
// (tile t+1 landed, t+2's 5 loads in flight), vmcnt(0) at t=62.
template <int B, bool STAGE, int VM, bool RDNEXT>
__device__ __forceinline__ void qkv_kstep(
        unsigned short* lds, f32x4 (&acc)[4][6],
        short8 (&aC)[4], short8 (&b0C)[3], short8 (&b1C)[3],   // tile t frags (regs)
        short8 (&aN)[4], short8 (&b0N)[3], short8 (&b1N)[3],   // tile t+1 frags (read here)
        const unsigned short*& p0, const unsigned short*& p1,
        const unsigned short*& p2, const unsigned short*& p3,
        const unsigned short*& p4,
        const int wave, const int aoff, const int boff) {
    constexpr int NXT = ((B + 1) % 3) * 10240;
    constexpr int DST = ((B + 2) % 3) * 10240;

    if constexpr (STAGE) {
        async_load16(p0, lds + DST + wave * 512);
        async_load16(p1, lds + DST + 2048 + wave * 512);
        async_load16(p2, lds + DST + 4096 + wave * 512);
        async_load16(p3, lds + DST + 6144 + wave * 512);
        async_load16(p4, lds + DST + 8192 + wave * 512);
    }
    p0 += 32; p1 += 32; p2 += 32; p3 += 32; p4 += 32;
    if constexpr (VM == 5)      asm volatile("s_waitcnt vmcnt(5)");
    else if constexpr (VM == 0) asm volatile("s_waitcnt vmcnt(0)");
    asm volatile("s_waitcnt lgkmcnt(0)");
    __builtin_amdgcn_s_barrier();
    if constexpr (RDNEXT) {
#pragma unroll
        for (int mf = 0; mf < 4; ++mf) aN[mf]  = *(const short8*)(lds + NXT + aoff + mf * 512);
#pragma unroll
        for (int nf = 0; nf < 3; ++nf) b0N[nf] = *(const short8*)(lds + NXT + boff + nf * 512);
#pragma unroll
        for (int nf = 0; nf < 3; ++nf) b1N[nf] = *(const short8*)(lds + NXT + boff + (3 + nf) * 512);
    }
    __builtin_amdgcn_s_setprio(1);
#pragma unroll
    for (int mf = 0; mf < 4; ++mf)
#pragma unroll
        for (int nf = 0; nf < 3; ++nf)
            acc[mf][nf] = __builtin_amdgcn_mfma_f32_16x16x32_bf16(aC[mf], b0C[nf], acc[mf][nf], 0, 0, 0);
#pragma unroll
    for (int mf = 0; mf < 4; ++mf)
#pragma unroll
        for (int nf = 0; nf < 3; ++nf)
            acc[mf][3 + nf] = __builtin_amdgcn_mfma_f32_16x16x32_bf16(aC[mf], b1C[nf], acc[mf][3 + nf], 0, 0, 0);
    __builtin_amdgcn_s_setprio(0);
}

__global__ __launch_bounds__(256, 2) void qkv_gemm192(
        const unsigned short* __restrict__ A,    // xb  [2048][2048]
        const unsigned short* __restrict__ Bm,   // wT  [6144][2048]
        unsigned short* __restrict__ Q,
        unsigned short* __restrict__ Kb,
        unsigned short* __restrict__ Vt) {
    extern __shared__ __attribute__((aligned(16))) unsigned short lds[];   // 60 KB ring-3
    const int mb = blockIdx.x, nb = blockIdx.y;   // nb = half-head column (192 wide)
    const int tid = threadIdx.x;                  // 256 threads = 4 waves
    const int wave = tid >> 6, lane = tid & 63;
    const int r = lane & 15, q = lane >> 4;
    const int wm = wave >> 1, wn = wave & 1;      // 2M x 2N wave grid, per-wave 64x96

    // staging: 1280 chunks/tile (A 512 + B 768), 5 chunks/thread, all uniform.
    // chunk c: row = (c>>6)*16 + ((c>>2)&15), kchunk = (c&3) ^ (((c>>2)&15)>>1 & 3).
    const int rrm = (tid >> 2) & 15;
    const int kg  = ((tid & 3) ^ ((rrm >> 1) & 3)) * 8;    // pre-swizzled global k
    const int row0g = (tid >> 6) * 16 + rrm;               // rows 0..63 (c = tid)
    const unsigned short* p0 = A  + (size_t)(mb * 128 + row0g) * DMODEL + kg;        // A rows 0..63
    const unsigned short* p1 = p0 + (size_t)64 * DMODEL;                             // A rows 64..127
    const unsigned short* p2 = Bm + (size_t)(nb * 192 + row0g) * DMODEL + kg;        // B rows 0..63
    const unsigned short* p3 = p2 + (size_t)64 * DMODEL;                             // B rows 64..127
    const unsigned short* p4 = p2 + (size_t)128 * DMODEL;                            // B rows 128..191

    // prologue: stage tiles 0,1 into bufs 0,1 (10 loads/thread)
#pragma unroll
    for (int t = 0; t < 2; ++t) {
        async_load16(p0 + t * 32, lds + t * 10240 + wave * 512);
        async_load16(p1 + t * 32, lds + t * 10240 + 2048 + wave * 512);
        async_load16(p2 + t * 32, lds + t * 10240 + 4096 + wave * 512);
        async_load16(p3 + t * 32, lds + t * 10240 + 6144 + wave * 512);
        async_load16(p4 + t * 32, lds + t * 10240 + 8192 + wave * 512);
    }
    p0 += 64; p1 += 64; p2 += 64; p3 += 64; p4 += 64;

    // fragment read offsets (shorts): slot XOR key is (r>>1)&3
    const int qs = q ^ ((r >> 1) & 3);
    const int aoff = wm * 2048 + r * 32 + qs * 8;
    const int boff = 4096 + wn * 3072 + r * 32 + qs * 8;

    f32x4 acc[4][6] = {};
    asm volatile("s_waitcnt vmcnt(5)");    // own tile-0 loads landed (tile-1 in flight)
    __builtin_amdgcn_s_barrier();          // -> ALL waves' tile-0 loads landed

    // tile-0 fragments (full set)
    short8 aA[4], b0A[3], b1A[3], aB[4], b0B[3], b1B[3];
#pragma unroll
    for (int mf = 0; mf < 4; ++mf) aA[mf]  = *(const short8*)(lds + aoff + mf * 512);
#pragma unroll
    for (int nf = 0; nf < 3; ++nf) b0A[nf] = *(const short8*)(lds + boff + nf * 512);
#pragma unroll
    for (int nf = 0; nf < 3; ++nf) b1A[nf] = *(const short8*)(lds + boff + (3 + nf) * 512);

    // 64 K-tiles: t=0..61 stage (t+2 <= 63); gates vmcnt(5); t=62 vm0; t=63 regs only.
    // 6-step body (ring-3 buffers x reg-set parity 2).
    for (int i = 0; i < 10; ++i) {
        qkv_kstep<0, true, 5, true>(lds, acc, aA, b0A, b1A, aB, b0B, b1B, p0, p1, p2, p3, p4, wave, aoff, boff);
        qkv_kstep<1, true, 5, true>(lds, acc, aB, b0B, b1B, aA, b0A, b1A, p0, p1, p2, p3, p4, wave, aoff, boff);
        qkv_kstep<2, true, 5, true>(lds, acc, aA, b0A, b1A, aB, b0B, b1B, p0, p1, p2, p3, p4, wave, aoff, boff);
        qkv_kstep<0, true, 5, true>(lds, acc, aB, b0B, b1B, aA, b0A, b1A, p0, p1, p2, p3, p4, wave, aoff, boff);
        qkv_kstep<1, true, 5, true>(lds, acc, aA, b0A, b1A, aB, b0B, b1B, p0, p1, p2, p3, p4, wave, aoff, boff);
        qkv_kstep<2, true, 5, true>(lds, acc, aB, b0B, b1B, aA, b0A, b1A, p0, p1, p2, p3, p4, wave, aoff, boff);
    }
    qkv_kstep<0, true,  5, true >(lds, acc, aA, b0A, b1A, aB, b0B, b1B, p0, p1, p2, p3, p4, wave, aoff, boff); // t=60
    qkv_kstep<1, true,  5, true >(lds, acc, aB, b0B, b1B, aA, b0A, b1A, p0, p1, p2, p3, p4, wave, aoff, boff); // t=61
    qkv_kstep<2, false, 0, true >(lds, acc, aA, b0A, b1A, aB, b0B, b1B, p0, p1, p2, p3, p4, wave, aoff, boff); // t=62
    qkv_kstep<0, false, -1, false>(lds, acc, aB, b0B, b1B, aA, b0A, b1A, p0, p1, p2, p3, p4, wave, aoff, boff); // t=63

    // epilogue: C frag (mf,nf): row = q*4+reg, col = r. nb = (head<<1)|half.
    const int head = nb >> 1;
    const int mbase = mb * 128 + wm * 64;
#pragma unroll
    for (int nf = 0; nf < 6; ++nf) {
        const int cb = (nb & 1) * 192 + wn * 96 + nf * 16;   // 0..368, multiple of 16
        const int sel = cb >> 7;                             // 0=Q 1=K 2=V (wave-uniform)
        const int e = (cb & 127) + r;
#pragma unroll
        for (int mf = 0; mf < 4; ++mf) {
            const int row0 = mbase + mf * 16 + q * 4;
            const f32x4 v = acc[mf][nf];
            if (sel == 2) {
                ushort4 o;
                o.x = f32_to_bf16(v[0]);
                o.y = f32_to_bf16(v[1]);
                o.z = f32_to_bf16(v[2]);
                o.w = f32_to_bf16(v[3]);
                *(ushort4*)&Vt[((size_t)head * EHEAD + e) * SEQ + row0] = o;
            } else {
                unsigned short* dst = sel ? Kb : Q;
#pragma unroll
                for (int reg = 0; reg < 4; ++reg)
                    dst[((size_t)head * SEQ + row0 + reg) * EHEAD + e] = f32_to_bf16(v[reg]);
            }
        }
    }
}

// ---------------- fused flash attention: 512 thr / 128 q / 256 blocks ----------------
// (unchanged from r8: 8 waves, per-wave dataflow verified; 4 waves/SIMD)
__global__ __launch_bounds__(512, 2) void flash_attn(
        const unsigned short* __restrict__ Qg,
        const unsigned short* __restrict__ Kg,
        const unsigned short* __restrict__ Vtg,
        float* __restrict__ out) {
    extern __shared__ __attribute__((aligned(16))) unsigned short lds[];
    unsigned short* sK0 = lds;            // 2 x 8192 shorts = 32 KB  [64 key][128 k]
    unsigned short* sV0 = lds + 16384;    // 2 x 8192 shorts = 32 KB  [128 e][64 key]

    const int tid = threadIdx.x;
    const int wave = tid >> 6, lane = tid & 63;
    const int l31 = lane & 31, q2 = lane >> 5;
    const int wm = wave >> 1, wn = wave & 1;   // wm 0..3 (query group), wn 0..1 (key half)
    const int b = blockIdx.x;                  // 256 blocks
    const int h  = (b & 7) + ((b >> 7) << 3);  // head -> XCD b%8 (2 heads/XCD, K/V L2-resident)
    const int m0 = ((b >> 3) & 15) * 128;

    const unsigned short* Qh  = Qg  + ((size_t)h * SEQ + m0) * EHEAD;
    const unsigned short* Kh0 = Kg  + (size_t)h * SEQ * EHEAD;
    const unsigned short* Vh  = Vtg + (size_t)h * EHEAD * SEQ;

    const int qkRow = lane >> 4;   // row within 4-row unit (K: 256B rows)
    const int qkPos = lane & 15;   // stored 16B-chunk position
    const int vRow  = lane >> 3;   // row within 8-row unit (V: 128B rows)
    const int vPos  = lane & 7;

    // ---- prologue: stage K/V tile 0 (2 units/wave each); Q -> registers ----
    const unsigned short* gK[2];
    const unsigned short* gV[2];
#pragma unroll
    for (int c = 0; c < 2; c++) {
        int u = wave * 2 + c;                 // 0..15
        int row = u * 4 + qkRow;              // 0..63
        int ch = qkPos ^ (row & 7);
        gK[c] = Kh0 + (size_t)row * EHEAD + ch * 8;
        int rv = u * 8 + vRow;                // 0..127
        int cv = vPos ^ (rv & 7);
        gV[c] = Vh + (size_t)rv * SEQ + cv * 8;
        async_load16(gK[c], sK0 + u * 512);
        async_load16(gV[c], sV0 + u * 512);
        gK[c] += 64 * EHEAD;   // next 64-key tile
        gV[c] += 64;
    }

    // resident Q fragments (B-operand of S^T = K·Q^T), loaded global->regs
    short8 bq[8];
    {
        const unsigned short* qrow = Qh + (size_t)(wm * 32 + l31) * EHEAD;
#pragma unroll
        for (int kc = 0; kc < 8; kc++)
            bq[kc] = *(const short8*)(qrow + (kc * 2 + q2) * 8);
    }
    __syncthreads();

    // hoisted per-lane LDS fragment pointers (buffer 0); buffer 1 = +8192 (imm)
    const unsigned short* kp[8];
    const unsigned short* vp[8];
    const int rowA = wn * 32 + l31;    // K fragment row (key within 64-tile)
#pragma unroll
    for (int kc = 0; kc < 8; kc++)
        kp[kc] = sK0 + rowA * 128 + (((kc * 2 + q2) ^ (rowA & 7)) * 8);
#pragma unroll
    for (int et = 0; et < 4; et++)
#pragma unroll
        for (int kc2 = 0; kc2 < 2; kc2++) {
            int rowV = et * 32 + l31;
            int cch = wn * 4 + kc2 * 2 + q2;
            vp[et * 2 + kc2] = sV0 + rowV * 64 + ((cch ^ (rowV & 7)) * 8);
        }

    const float c1 = 0.12752405856f;   // (1/sqrt(128)) * log2(e)
    f32x16 acc_o[4] = {};              // partial O: 32 m x 128 e (keys of this wn)
    float l_acc0 = 0.f, l_acc1 = 0.f;  // split l chains

    auto body = [&](const int cur, const int nxt, bool pref) {
        if (pref) {
#pragma unroll
            for (int c = 0; c < 2; c++) {
                async_load16(gK[c], sK0 + nxt + (wave * 2 + c) * 512);
                gK[c] += 64 * EHEAD;
            }
#pragma unroll
            for (int c = 0; c < 2; c++) {
                async_load16(gV[c], sV0 + nxt + (wave * 2 + c) * 512);
                gV[c] += 64;
            }
        }

        // ---- S^T = K · Q^T (32 keys x 32 queries), two independent chains ----
        f32x16 st0 = {}, st1 = {};
        __builtin_amdgcn_s_setprio(1);
#pragma unroll
        for (int kc = 0; kc < 8; kc += 2) {
            short8 ak0 = *(const short8*)(kp[kc] + cur);
            short8 ak1 = *(const short8*)(kp[kc + 1] + cur);
            st0 = __builtin_amdgcn_mfma_f32_32x32x16_bf16(ak0, bq[kc], st0, 0, 0, 0);
            st1 = __builtin_amdgcn_mfma_f32_32x32x16_bf16(ak1, bq[kc + 1], st1, 0, 0, 0);
        }
        __builtin_amdgcn_s_setprio(0);

        // ---- P = exp2(s*c1), per-lane l, v_perm bf16 pack ----
        unsigned int pk[8];
#pragma unroll
        for (int t = 0; t < 8; t++) {
            float p0 = __builtin_amdgcn_exp2f((st0[2 * t] + st1[2 * t]) * c1);
            float p1 = __builtin_amdgcn_exp2f((st0[2 * t + 1] + st1[2 * t + 1]) * c1);
            l_acc0 += p0;
            l_acc1 += p1;
            unsigned int u0 = __float_as_uint(p0) + 0x8000u;
            unsigned int u1 = __float_as_uint(p1) + 0x8000u;
            pk[t] = __builtin_amdgcn_perm(u1, u0, 0x07060302u);   // {bf16(p1),bf16(p0)}
        }

        // ---- build P A-fragments: half-wave exchange via permlane32_swap ----
        short8 fr[2];
#pragma unroll
        for (int kc2 = 0; kc2 < 2; kc2++) {
            unsigned int a0 = pk[kc2 * 4 + 0], a1 = pk[kc2 * 4 + 1];
            unsigned int a2 = pk[kc2 * 4 + 2], a3 = pk[kc2 * 4 + 3];
            uint2v r02 = __builtin_amdgcn_permlane32_swap(a0, a2, false, false);
            uint2v r13 = __builtin_amdgcn_permlane32_swap(a1, a3, false, false);
            uint4v t;
            t.x = r02[0];
            t.y = r13[0];
            t.z = r02[1];
            t.w = r13[1];
            fr[kc2] = __builtin_bit_cast(short8, t);
        }

        // ---- O_partial += P · V over this wave's 32 keys ----
        __builtin_amdgcn_s_setprio(1);
#pragma unroll
        for (int et = 0; et < 4; et++)
#pragma unroll
            for (int kc2 = 0; kc2 < 2; kc2++) {
                short8 bv = *(const short8*)(vp[et * 2 + kc2] + cur);
                acc_o[et] = __builtin_amdgcn_mfma_f32_32x32x16_bf16(fr[kc2], bv, acc_o[et], 0, 0, 0);
            }
        __builtin_amdgcn_s_setprio(0);
        __syncthreads();   // reads of cur done; prefetch into nxt drained
    };

    for (int ip = 0; ip < SEQ / 128; ip++) {
        body(0, 8192, true);                  // even tile in buf0, prefetch -> buf1
        body(8192, 0, ip != SEQ / 128 - 1);   // odd tile in buf1, prefetch -> buf0
    }

    // ---- epilogue (all acc_o indices compile-time) ----
    float l_acc = l_acc0 + l_acc1;
    l_acc += __shfl_xor(l_acc, 32);    // combine half-wave key halves

    float* fl = (float*)lds;           // O-exchange [0,16384) + l [16384,16640) floats
#pragma unroll
    for (int et = 0; et < 4; et++) {
        if ((et >> 1) != wn) {
#pragma unroll
            for (int rg = 0; rg < 4; rg++) {
                f32x4 v;
                v[0] = acc_o[et][rg * 4 + 0];
                v[1] = acc_o[et][rg * 4 + 1];
                v[2] = acc_o[et][rg * 4 + 2];
                v[3] = acc_o[et][rg * 4 + 3];
                *(f32x4*)&fl[(size_t)(((wm * 4 + et) * 4 + rg) * 256) + lane * 4] = v;
            }
        }
    }
    fl[16384 + (wm * 2 + wn) * 32 + l31] = l_acc;   // l partial, indexed by QUERY
    __syncthreads();

    float invq[4][4];
#pragma unroll
    for (int rg = 0; rg < 4; rg++)
#pragma unroll
        for (int i = 0; i < 4; i++) {
            int qy = i + 4 * q2 + 8 * rg;
            float lt = fl[16384 + (wm * 2 + 0) * 32 + qy] + fl[16384 + (wm * 2 + 1) * 32 + qy];
            invq[rg][i] = 1.0f / lt;
        }

#pragma unroll
    for (int et = 0; et < 4; et++) {
        if ((et >> 1) == wn) {
#pragma unroll
            for (int rg = 0; rg < 4; rg++) {
                f32x4 v = *(const f32x4*)&fl[(size_t)(((wm * 4 + et) * 4 + rg) * 256) + lane * 4];
#pragma unroll
                for (int i = 0; i < 4; i++) {
                    int mrow = i + 4 * q2 + 8 * rg;
                    out[(size_t)(m0 + wm * 32 + mrow) * DMODEL + h * EHEAD + et * 32 + l31] =
                        (acc_o[et][rg * 4 + i] + v[i]) * invq[rg][i];
                }
            }
        }
    }
}

extern "C" void kernel_launch(void* const* d_in, const int* in_sizes, int n_in,
                              void* d_out, int out_size, void* d_ws, size_t ws_size,
                              hipStream_t stream) {
    const float* x = (const float*)d_in[0];      // [S][D]
    const float* w = (const float*)d_in[1];      // [H][D][3E]
    float* out = (float*)d_out;                  // [S][H*E]

    char* ws = (char*)d_ws;
    unsigned short* xb = (unsigned short*)(ws);                        //  8 MB
    unsigned short* wT = (unsigned short*)(ws + 8388608);              // 24 MB
    unsigned short* Q  = (unsigned short*)(ws + 33554432);             //  8 MB
    unsigned short* Kb = (unsigned short*)(ws + 41943040);             //  8 MB
    unsigned short* Vt = (unsigned short*)(ws + 50331648);             //  8 MB

    static bool attr_set = false;
    if (!attr_set) {
        hipFuncSetAttribute((const void*)flash_attn,
                            hipFuncAttributeMaxDynamicSharedMemorySize, 66560);
        hipFuncSetAttribute((const void*)qkv_gemm192,
                            hipFuncAttributeMaxDynamicSharedMemorySize, 61440);
        attr_set = true;
    }

    prep_kernel<<<7168, 256, 0, stream>>>(x, xb, w, wT);
    qkv_gemm192<<<dim3(SEQ / 128, NHEAD * 2), 256, 61440, stream>>>(xb, wT, Q, Kb, Vt);
    flash_attn<<<256, 512, 66560, stream>>>(Q, Kb, Vt, out);
}

// Round 10
// 189.199 us; speedup vs baseline: 1.0555x; 1.0555x over previous
//
#include <hip/hip_runtime.h>

#define SEQ 2048
#define DMODEL 2048
#define NHEAD 16
#define EHEAD 128
#define NE3 384   // 3*EHEAD

using short8 = __attribute__((ext_vector_type(8))) short;
using f32x4  = __attribute__((ext_vector_type(4))) float;
using f32x16 = __attribute__((ext_vector_type(16))) float;
using uint4v = __attribute__((ext_vector_type(4))) unsigned int;
using uint2v = __attribute__((ext_vector_type(2))) unsigned int;

__device__ __forceinline__ unsigned short f32_to_bf16(float f) {
    unsigned int u = __float_as_uint(f);
    unsigned int rounding = 0x7fffu + ((u >> 16) & 1u);
    u += rounding;
    return (unsigned short)(u >> 16);
}

// async global->LDS, 16B/lane; LDS dest = wave-uniform base + lane*16B.
__device__ __forceinline__ void async_load16(const void* g, void* l) {
    __builtin_amdgcn_global_load_lds(
        (const __attribute__((address_space(1))) unsigned int*)g,
        (__attribute__((address_space(3))) unsigned int*)l, 16, 0, 0);
}

// ---------------- fused prep: cast x (blocks 0..4095) + transpose w (4096..7167) ----------------
__global__ void prep_kernel(const float* __restrict__ x, unsigned short* __restrict__ xb,
                            const float* __restrict__ w, unsigned short* __restrict__ wT) {
    __shared__ float tile[64][65];
    const int bid = blockIdx.x;
    if (bid < 4096) {
        int i = (bid * blockDim.x + threadIdx.x) * 4;
        float4 v = *(const float4*)(x + i);
        ushort4 o = make_ushort4(f32_to_bf16(v.x), f32_to_bf16(v.y), f32_to_bf16(v.z), f32_to_bf16(v.w));
        *(ushort4*)(xb + i) = o;
        return;
    }
    const int b = bid - 4096;          // 3072 transpose blocks: h 16 x n0 6 x d0 32
    const int h  = b / 192;
    const int r6 = b % 192;
    const int n0 = (r6 / 32) * 64;
    const int d0 = (r6 % 32) * 64;
    int t = threadIdx.x;
    int rr = t >> 4;           // 0..15
    int cc = (t & 15) * 4;     // 0..60
#pragma unroll
    for (int i = 0; i < 4; i++) {
        float4 v = *(const float4*)&w[(size_t)(h * DMODEL + d0 + rr + i * 16) * NE3 + n0 + cc];
        tile[rr + i * 16][cc + 0] = v.x;
        tile[rr + i * 16][cc + 1] = v.y;
        tile[rr + i * 16][cc + 2] = v.z;
        tile[rr + i * 16][cc + 3] = v.w;
    }
    __syncthreads();
#pragma unroll
    for (int i = 0; i < 4; i++) {
        int n = rr + i * 16;
        ushort4 o;
        o.x = f32_to_bf16(tile[cc + 0][n]);
        o.y = f32_to_bf16(tile[cc + 1][n]);
        o.z = f32_to_bf16(tile[cc + 2][n]);
        o.w = f32_to_bf16(tile[cc + 3][n]);
        *(ushort4*)&wT[(size_t)(h * NE3 + n0 + n) * DMODEL + d0 + cc] = o;
    }
}

// ---------------- QKV projection: 128x384 tile (one head per block), BK=32 ----------------
// r10 = r8 core (verified 57.2 us / MfmaUtil 38%: merged single-phase K-step, ring-4,
// 2-tile prefetch slack — r9's ring-3 regression proved the slack matters) plus:
// (a) XCD swizzle: wgid -> xcd=wgid%8, idx=wgid/8; nb = 2*xcd + (idx>>4), mb = idx&15.
//     Each XCD owns 2 heads x all m-tiles -> its 2 B-panels (3 MB) stay L2-resident.
// (b) Q-fragments pre-scaled by c1 = log2(e)/sqrt(128) at the epilogue (folds the
//     softmax scale out of the attn hot loop; Q is workspace-only).
template <int B, bool STAGE, int VM, bool RDNEXT>
__device__ __forceinline__ void qkv_kstep(
        unsigned short* lds, f32x4 (&acc)[4][6],
        short8 (&aC)[4], short8 (&b0C)[3], short8 (&b1C)[3],   // tile t frags (regs)
        short8 (&aN)[4], short8 (&b0N)[3], short8 (&b1N)[3],   // tile t+1 frags (read here)
        const unsigned short*& p0, const unsigned short*& p1,
        const unsigned short*& p2, const unsigned short*& p3,
        const int d0, const int d1, const int d2, const int d3,
        const int aoff, const int boff) {
    constexpr int NXT = ((B + 1) & 3) * 16384;
    constexpr int DST = ((B + 3) & 3) * 16384;

    if constexpr (STAGE) {
        async_load16(p0, lds + DST + d0);
        async_load16(p1, lds + DST + d1);
        async_load16(p2, lds + DST + d2);
        async_load16(p3, lds + DST + d3);
    }
    p0 += 32; p1 += 32; p2 += 32; p3 += 32;
    if constexpr (VM == 8)      asm volatile("s_waitcnt vmcnt(8)");
    else if constexpr (VM == 4) asm volatile("s_waitcnt vmcnt(4)");
    else if constexpr (VM == 0) asm volatile("s_waitcnt vmcnt(0)");
    asm volatile("s_waitcnt lgkmcnt(0)");
    __builtin_amdgcn_s_barrier();
    if constexpr (RDNEXT) {
#pragma unroll
        for (int mf = 0; mf < 4; ++mf) aN[mf]  = *(const short8*)(lds + NXT + aoff + mf * 512);
#pragma unroll
        for (int nf = 0; nf < 3; ++nf) b0N[nf] = *(const short8*)(lds + NXT + boff + nf * 512);
#pragma unroll
        for (int nf = 0; nf < 3; ++nf) b1N[nf] = *(const short8*)(lds + NXT + boff + (3 + nf) * 512);
    }
    __builtin_amdgcn_s_setprio(1);
#pragma unroll
    for (int mf = 0; mf < 4; ++mf)
#pragma unroll
        for (int nf = 0; nf < 3; ++nf)
            acc[mf][nf] = __builtin_amdgcn_mfma_f32_16x16x32_bf16(aC[mf], b0C[nf], acc[mf][nf], 0, 0, 0);
#pragma unroll
    for (int mf = 0; mf < 4; ++mf)
#pragma unroll
        for (int nf = 0; nf < 3; ++nf)
            acc[mf][3 + nf] = __builtin_amdgcn_mfma_f32_16x16x32_bf16(aC[mf], b1C[nf], acc[mf][3 + nf], 0, 0, 0);
    __builtin_amdgcn_s_setprio(0);
}

__global__ __launch_bounds__(512, 2) void qkv_gemm384(
        const unsigned short* __restrict__ A,    // xb  [2048][2048]
        const unsigned short* __restrict__ Bm,   // wT  [6144][2048]
        unsigned short* __restrict__ Q,
        unsigned short* __restrict__ Kb,
        unsigned short* __restrict__ Vt) {
    extern __shared__ __attribute__((aligned(16))) unsigned short lds[];   // 128 KB
    // XCD swizzle: 256 wgs, 1/CU; hw xcd = wgid%8. nb = 2*xcd + (idx>>4), mb = idx&15.
    const int wgid = blockIdx.x;
    const int xcd = wgid & 7, idx = wgid >> 3;
    const int mb = idx & 15;
    const int nb = (xcd << 1) + (idx >> 4);       // nb == head
    const int tid = threadIdx.x;
    const int wave = tid >> 6, lane = tid & 63;
    const int r = lane & 15, q = lane >> 4;
    const int wm = wave >> 2, wn = wave & 3;      // 2M x 4N wave grid, per-wave 64x96

    // staging: 2048 chunks/tile (A 512 + B 1536), 4 chunks/thread, all uniform.
    const int rrm  = (tid >> 2) & 15;
    const int kg   = ((tid & 3) ^ ((rrm >> 1) & 3)) * 8;   // pre-swizzled global k
    const int rowA = ((tid >> 6) << 4) + rrm;              // 0..127
    const unsigned short* p0 = A  + (size_t)(mb * 128 + rowA) * DMODEL + kg;
    const unsigned short* p1 = Bm + (size_t)(nb * 384 + rowA) * DMODEL + kg;
    const unsigned short* p2 = p1 + (size_t)128 * DMODEL;
    const unsigned short* p3 = p1 + (size_t)256 * DMODEL;
    const int d0 = wave * 512;                 // LDS dests (shorts, wave-uniform)
    const int d1 = 4096 + wave * 512;
    const int d2 = 8192 + wave * 512;
    const int d3 = 12288 + wave * 512;

    // prologue: stage tiles 0..2 into bufs 0..2
#pragma unroll
    for (int t = 0; t < 3; ++t) {
        async_load16(p0 + t * 32, lds + t * 16384 + d0);
        async_load16(p1 + t * 32, lds + t * 16384 + d1);
        async_load16(p2 + t * 32, lds + t * 16384 + d2);
        async_load16(p3 + t * 32, lds + t * 16384 + d3);
    }
    p0 += 96; p1 += 96; p2 += 96; p3 += 96;

    // fragment read offsets (shorts): slot XOR key is (r>>1)&3
    const int qs = q ^ ((r >> 1) & 3);
    const int aoff = wm * 2048 + r * 32 + qs * 8;
    const int boff = 4096 + wn * 3072 + r * 32 + qs * 8;

    f32x4 acc[4][6] = {};
    asm volatile("s_waitcnt vmcnt(8)");   // own tile-0 loads landed
    __builtin_amdgcn_s_barrier();          // -> ALL waves' tile-0 loads landed

    // tile-0 fragments (full set)
    short8 aA[4], b0A[3], b1A[3], aB[4], b0B[3], b1B[3];
#pragma unroll
    for (int mf = 0; mf < 4; ++mf) aA[mf]  = *(const short8*)(lds + aoff + mf * 512);
#pragma unroll
    for (int nf = 0; nf < 3; ++nf) b0A[nf] = *(const short8*)(lds + boff + nf * 512);
#pragma unroll
    for (int nf = 0; nf < 3; ++nf) b1A[nf] = *(const short8*)(lds + boff + (3 + nf) * 512);

    // 64 K-tiles: t=0..60 steady (stage, vmcnt(8)); 61/62/63 drain 4/0/none.
    for (int i = 0; i < 15; ++i) {
        qkv_kstep<0, true, 8, true>(lds, acc, aA, b0A, b1A, aB, b0B, b1B, p0, p1, p2, p3, d0, d1, d2, d3, aoff, boff);
        qkv_kstep<1, true, 8, true>(lds, acc, aB, b0B, b1B, aA, b0A, b1A, p0, p1, p2, p3, d0, d1, d2, d3, aoff, boff);
        qkv_kstep<2, true, 8, true>(lds, acc, aA, b0A, b1A, aB, b0B, b1B, p0, p1, p2, p3, d0, d1, d2, d3, aoff, boff);
        qkv_kstep<3, true, 8, true>(lds, acc, aB, b0B, b1B, aA, b0A, b1A, p0, p1, p2, p3, d0, d1, d2, d3, aoff, boff);
    }
    qkv_kstep<0, true,  8, true >(lds, acc, aA, b0A, b1A, aB, b0B, b1B, p0, p1, p2, p3, d0, d1, d2, d3, aoff, boff); // t=60
    qkv_kstep<1, false, 4, true >(lds, acc, aB, b0B, b1B, aA, b0A, b1A, p0, p1, p2, p3, d0, d1, d2, d3, aoff, boff); // t=61
    qkv_kstep<2, false, 0, true >(lds, acc, aA, b0A, b1A, aB, b0B, b1B, p0, p1, p2, p3, d0, d1, d2, d3, aoff, boff); // t=62
    qkv_kstep<3, false, -1, false>(lds, acc, aB, b0B, b1B, aA, b0A, b1A, p0, p1, p2, p3, d0, d1, d2, d3, aoff, boff); // t=63

    // epilogue: C frag (mf,nf): row = q*4+reg, col = r. One head per block.
    // Q-fragments pre-scaled by c1 (softmax scale folded out of attn).
    const float c1 = 0.12752405856f;   // (1/sqrt(128)) * log2(e)
    const int head = nb;
    const int mbase = mb * 128 + wm * 64;
#pragma unroll
    for (int nf = 0; nf < 6; ++nf) {
        const int cb = wn * 96 + nf * 16;        // 0..368, multiple of 16
        const int sel = cb >> 7;                 // 0=Q 1=K 2=V (wave-uniform)
        const int e = (cb & 127) + r;
#pragma unroll
        for (int mf = 0; mf < 4; ++mf) {
            const int row0 = mbase + mf * 16 + q * 4;
            f32x4 v = acc[mf][nf];
            if (sel == 2) {
                ushort4 o;
                o.x = f32_to_bf16(v[0]);
                o.y = f32_to_bf16(v[1]);
                o.z = f32_to_bf16(v[2]);
                o.w = f32_to_bf16(v[3]);
                *(ushort4*)&Vt[((size_t)head * EHEAD + e) * SEQ + row0] = o;
            } else {
                if (sel == 0) {
#pragma unroll
                    for (int reg = 0; reg < 4; ++reg) v[reg] *= c1;
                }
                unsigned short* dst = sel ? Kb : Q;
#pragma unroll
                for (int reg = 0; reg < 4; ++reg)
                    dst[((size_t)head * SEQ + row0 + reg) * EHEAD + e] = f32_to_bf16(v[reg]);
            }
        }
    }
}

// ---------------- fused flash attention: 512 thr / 128 q / 256 blocks ----------------
// r10 vs r8: single QK^T MFMA chain (removes 16 st0+st1 adds/body — 4 waves/SIMD TLP
// already hides MFMA latency, r5's split chain was null) and no c1 mul (Q pre-scaled).
__global__ __launch_bounds__(512, 2) void flash_attn(
        const unsigned short* __restrict__ Qg,
        const unsigned short* __restrict__ Kg,
        const unsigned short* __restrict__ Vtg,
        float* __restrict__ out) {
    extern __shared__ __attribute__((aligned(16))) unsigned short lds[];
    unsigned short* sK0 = lds;            // 2 x 8192 shorts = 32 KB  [64 key][128 k]
    unsigned short* sV0 = lds + 16384;    // 2 x 8192 shorts = 32 KB  [128 e][64 key]

    const int tid = threadIdx.x;
    const int wave = tid >> 6, lane = tid & 63;
    const int l31 = lane & 31, q2 = lane >> 5;
    const int wm = wave >> 1, wn = wave & 1;   // wm 0..3 (query group), wn 0..1 (key half)
    const int b = blockIdx.x;                  // 256 blocks
    const int h  = (b & 7) + ((b >> 7) << 3);  // head -> XCD b%8 (2 heads/XCD, K/V L2-resident)
    const int m0 = ((b >> 3) & 15) * 128;

    const unsigned short* Qh  = Qg  + ((size_t)h * SEQ + m0) * EHEAD;
    const unsigned short* Kh0 = Kg  + (size_t)h * SEQ * EHEAD;
    const unsigned short* Vh  = Vtg + (size_t)h * EHEAD * SEQ;

    const int qkRow = lane >> 4;   // row within 4-row unit (K: 256B rows)
    const int qkPos = lane & 15;   // stored 16B-chunk position
    const int vRow  = lane >> 3;   // row within 8-row unit (V: 128B rows)
    const int vPos  = lane & 7;

    // ---- prologue: stage K/V tile 0 (2 units/wave each); Q -> registers ----
    const unsigned short* gK[2];
    const unsigned short* gV[2];
#pragma unroll
    for (int c = 0; c < 2; c++) {
        int u = wave * 2 + c;                 // 0..15
        int row = u * 4 + qkRow;              // 0..63
        int ch = qkPos ^ (row & 7);
        gK[c] = Kh0 + (size_t)row * EHEAD + ch * 8;
        int rv = u * 8 + vRow;                // 0..127
        int cv = vPos ^ (rv & 7);
        gV[c] = Vh + (size_t)rv * SEQ + cv * 8;
        async_load16(gK[c], sK0 + u * 512);
        async_load16(gV[c], sV0 + u * 512);
        gK[c] += 64 * EHEAD;   // next 64-key tile
        gV[c] += 64;
    }

    // resident Q fragments (B-operand of S^T = K·Q^T), loaded global->regs (pre-scaled by c1)
    short8 bq[8];
    {
        const unsigned short* qrow = Qh + (size_t)(wm * 32 + l31) * EHEAD;
#pragma unroll
        for (int kc = 0; kc < 8; kc++)
            bq[kc] = *(const short8*)(qrow + (kc * 2 + q2) * 8);
    }
    __syncthreads();

    // hoisted per-lane LDS fragment pointers (buffer 0); buffer 1 = +8192 (imm)
    const unsigned short* kp[8];
    const unsigned short* vp[8];
    const int rowA = wn * 32 + l31;    // K fragment row (key within 64-tile)
#pragma unroll
    for (int kc = 0; kc < 8; kc++)
        kp[kc] = sK0 + rowA * 128 + (((kc * 2 + q2) ^ (rowA & 7)) * 8);
#pragma unroll
    for (int et = 0; et < 4; et++)
#pragma unroll
        for (int kc2 = 0; kc2 < 2; kc2++) {
            int rowV = et * 32 + l31;
            int cch = wn * 4 + kc2 * 2 + q2;
            vp[et * 2 + kc2] = sV0 + rowV * 64 + ((cch ^ (rowV & 7)) * 8);
        }

    f32x16 acc_o[4] = {};              // partial O: 32 m x 128 e (keys of this wn)
    float l_acc0 = 0.f, l_acc1 = 0.f;  // split l chains

    auto body = [&](const int cur, const int nxt, bool pref) {
        if (pref) {
#pragma unroll
            for (int c = 0; c < 2; c++) {
                async_load16(gK[c], sK0 + nxt + (wave * 2 + c) * 512);
                gK[c] += 64 * EHEAD;
            }
#pragma unroll
            for (int c = 0; c < 2; c++) {
                async_load16(gV[c], sV0 + nxt + (wave * 2 + c) * 512);
                gV[c] += 64;
            }
        }

        // ---- S^T = K · Q^T (32 keys x 32 queries), single chain (c1 folded into Q) ----
        f32x16 st = {};
        __builtin_amdgcn_s_setprio(1);
#pragma unroll
        for (int kc = 0; kc < 8; kc++) {
            short8 ak = *(const short8*)(kp[kc] + cur);
            st = __builtin_amdgcn_mfma_f32_32x32x16_bf16(ak, bq[kc], st, 0, 0, 0);
        }
        __builtin_amdgcn_s_setprio(0);

        // ---- P = exp2(s), per-lane l, v_perm bf16 pack ----
        unsigned int pk[8];
#pragma unroll
        for (int t = 0; t < 8; t++) {
            float p0 = __builtin_amdgcn_exp2f(st[2 * t]);
            float p1 = __builtin_amdgcn_exp2f(st[2 * t + 1]);
            l_acc0 += p0;
            l_acc1 += p1;
            unsigned int u0 = __float_as_uint(p0) + 0x8000u;
            unsigned int u1 = __float_as_uint(p1) + 0x8000u;
            pk[t] = __builtin_amdgcn_perm(u1, u0, 0x07060302u);   // {bf16(p1),bf16(p0)}
        }

        // ---- build P A-fragments: half-wave exchange via permlane32_swap ----
        short8 fr[2];
#pragma unroll
        for (int kc2 = 0; kc2 < 2; kc2++) {
            unsigned int a0 = pk[kc2 * 4 + 0], a1 = pk[kc2 * 4 + 1];
            unsigned int a2 = pk[kc2 * 4 + 2], a3 = pk[kc2 * 4 + 3];
            uint2v r02 = __builtin_amdgcn_permlane32_swap(a0, a2, false, false);
            uint2v r13 = __builtin_amdgcn_permlane32_swap(a1, a3, false, false);
            uint4v t;
            t.x = r02[0];
            t.y = r13[0];
            t.z = r02[1];
            t.w = r13[1];
            fr[kc2] = __builtin_bit_cast(short8, t);
        }

        // ---- O_partial += P · V over this wave's 32 keys ----
        __builtin_amdgcn_s_setprio(1);
#pragma unroll
        for (int et = 0; et < 4; et++)
#pragma unroll
            for (int kc2 = 0; kc2 < 2; kc2++) {
                short8 bv = *(const short8*)(vp[et * 2 + kc2] + cur);
                acc_o[et] = __builtin_amdgcn_mfma_f32_32x32x16_bf16(fr[kc2], bv, acc_o[et], 0, 0, 0);
            }
        __builtin_amdgcn_s_setprio(0);
        __syncthreads();   // reads of cur done; prefetch into nxt drained
    };

    for (int ip = 0; ip < SEQ / 128; ip++) {
        body(0, 8192, true);                  // even tile in buf0, prefetch -> buf1
        body(8192, 0, ip != SEQ / 128 - 1);   // odd tile in buf1, prefetch -> buf0
    }

    // ---- epilogue (all acc_o indices compile-time) ----
    float l_acc = l_acc0 + l_acc1;
    l_acc += __shfl_xor(l_acc, 32);    // combine half-wave key halves

    float* fl = (float*)lds;           // O-exchange [0,16384) + l [16384,16640) floats
#pragma unroll
    for (int et = 0; et < 4; et++) {
        if ((et >> 1) != wn) {
#pragma unroll
            for (int rg = 0; rg < 4; rg++) {
                f32x4 v;
                v[0] = acc_o[et][rg * 4 + 0];
                v[1] = acc_o[et][rg * 4 + 1];
                v[2] = acc_o[et][rg * 4 + 2];
                v[3] = acc_o[et][rg * 4 + 3];
                *(f32x4*)&fl[(size_t)(((wm * 4 + et) * 4 + rg) * 256) + lane * 4] = v;
            }
        }
    }
    fl[16384 + (wm * 2 + wn) * 32 + l31] = l_acc;   // l partial, indexed by QUERY
    __syncthreads();

    float invq[4][4];
#pragma unroll
    for (int rg = 0; rg < 4; rg++)
#pragma unroll
        for (int i = 0; i < 4; i++) {
            int qy = i + 4 * q2 + 8 * rg;
            float lt = fl[16384 + (wm * 2 + 0) * 32 + qy] + fl[16384 + (wm * 2 + 1) * 32 + qy];
            invq[rg][i] = 1.0f / lt;
        }

#pragma unroll
    for (int et = 0; et < 4; et++) {
        if ((et >> 1) == wn) {
#pragma unroll
            for (int rg = 0; rg < 4; rg++) {
                f32x4 v = *(const f32x4*)&fl[(size_t)(((wm * 4 + et) * 4 + rg) * 256) + lane * 4];
#pragma unroll
                for (int i = 0; i < 4; i++) {
                    int mrow = i + 4 * q2 + 8 * rg;
                    out[(size_t)(m0 + wm * 32 + mrow) * DMODEL + h * EHEAD + et * 32 + l31] =
                        (acc_o[et][rg * 4 + i] + v[i]) * invq[rg][i];
                }
            }
        }
    }
}

extern "C" void kernel_launch(void* const* d_in, const int* in_sizes, int n_in,
                              void* d_out, int out_size, void* d_ws, size_t ws_size,
                              hipStream_t stream) {
    const float* x = (const float*)d_in[0];      // [S][D]
    const float* w = (const float*)d_in[1];      // [H][D][3E]
    float* out = (float*)d_out;                  // [S][H*E]

    char* ws = (char*)d_ws;
    unsigned short* xb = (unsigned short*)(ws);                        //  8 MB
    unsigned short* wT = (unsigned short*)(ws + 8388608);              // 24 MB
    unsigned short* Q  = (unsigned short*)(ws + 33554432);             //  8 MB
    unsigned short* Kb = (unsigned short*)(ws + 41943040);             //  8 MB
    unsigned short* Vt = (unsigned short*)(ws + 50331648);             //  8 MB

    static bool attr_set = false;
    if (!attr_set) {
        hipFuncSetAttribute((const void*)flash_attn,
                            hipFuncAttributeMaxDynamicSharedMemorySize, 66560);
        hipFuncSetAttribute((const void*)qkv_gemm384,
                            hipFuncAttributeMaxDynamicSharedMemorySize, 131072);
        attr_set = true;
    }

    prep_kernel<<<7168, 256, 0, stream>>>(x, xb, w, wT);
    qkv_gemm384<<<256, 512, 131072, stream>>>(xb, wT, Q, Kb, Vt);
    flash_attn<<<256, 512, 66560, stream>>>(Q, Kb, Vt, out);
}